// Round 6
// baseline (362.249 us; speedup 1.0000x reference)
//
#include <hip/hip_runtime.h>
#include <math.h>

#define D_DIM 2048
#define R_DIM 512
#define E_NUM 8
#define B_NUM 8
#define S_NUM 2048
#define M_DIM 16384
#define LN_EPS 1e-5f

typedef __attribute__((ext_vector_type(8))) short bf16x8;
typedef __attribute__((ext_vector_type(4))) float f32x4;

// Manual RNE float->bf16 (inputs finite/normal; no NaN path needed)
__device__ __forceinline__ unsigned short f2bf(float f) {
    unsigned u = __float_as_uint(f);
    return (unsigned short)((u + 0x7FFFu + ((u >> 16) & 1u)) >> 16);
}

__device__ __forceinline__ void gload_lds16(const void* g, void* l) {
    __builtin_amdgcn_global_load_lds(
        (const __attribute__((address_space(1))) void*)g,
        (__attribute__((address_space(3))) void*)l, 16, 0, 0);
}

// ---------------------------------------------------------------------------
// Fused prep kernel, one dispatch:
//   blocks [0, 16384):      per-token LayerNorm -> bf16 in place (first 4KB/row)
//   blocks [16384, 17408):  w1[k][n] fp32 -> wT[n][k] bf16 (transpose + round)
//   blocks [17408, 17424):  zero hsum (4096 floats)
// ---------------------------------------------------------------------------
__global__ __launch_bounds__(256) void prep_kernel(float* __restrict__ x,
                                                   const float* __restrict__ gamma,
                                                   const float* __restrict__ beta,
                                                   const float* __restrict__ w1,
                                                   unsigned short* __restrict__ wt,
                                                   float* __restrict__ zbuf) {
    const int t = threadIdx.x;
    if (blockIdx.x < M_DIM) {
        // ---- LayerNorm + bf16 pack, in place ----
        __shared__ float sred[8];
        float* row = x + (size_t)blockIdx.x * D_DIM;
        const float4 v0  = ((const float4*)row)[t];
        const float4 v1  = ((const float4*)row)[t + 256];
        const float4 g0  = ((const float4*)gamma)[t];
        const float4 g1  = ((const float4*)gamma)[t + 256];
        const float4 be0 = ((const float4*)beta)[t];
        const float4 be1 = ((const float4*)beta)[t + 256];

        float s  = v0.x + v0.y + v0.z + v0.w + v1.x + v1.y + v1.z + v1.w;
        float sq = v0.x*v0.x + v0.y*v0.y + v0.z*v0.z + v0.w*v0.w
                 + v1.x*v1.x + v1.y*v1.y + v1.z*v1.z + v1.w*v1.w;
#pragma unroll
        for (int off = 32; off > 0; off >>= 1) {
            s  += __shfl_down(s, off);
            sq += __shfl_down(sq, off);
        }
        if ((t & 63) == 0) { sred[(t >> 6) * 2] = s; sred[(t >> 6) * 2 + 1] = sq; }
        __syncthreads();            // also: all reads of `row` are complete
        s  = sred[0] + sred[2] + sred[4] + sred[6];
        sq = sred[1] + sred[3] + sred[5] + sred[7];
        const float mu  = s * (1.f / D_DIM);
        const float var = sq * (1.f / D_DIM) - mu * mu;
        const float rs  = rsqrtf(var + LN_EPS);

        ushort4 h0, h1;
        h0.x = f2bf(fmaf((v0.x - mu) * rs, g0.x, be0.x));
        h0.y = f2bf(fmaf((v0.y - mu) * rs, g0.y, be0.y));
        h0.z = f2bf(fmaf((v0.z - mu) * rs, g0.z, be0.z));
        h0.w = f2bf(fmaf((v0.w - mu) * rs, g0.w, be0.w));
        h1.x = f2bf(fmaf((v1.x - mu) * rs, g1.x, be1.x));
        h1.y = f2bf(fmaf((v1.y - mu) * rs, g1.y, be1.y));
        h1.z = f2bf(fmaf((v1.z - mu) * rs, g1.z, be1.z));
        h1.w = f2bf(fmaf((v1.w - mu) * rs, g1.w, be1.w));

        ushort4* rowu = (ushort4*)row;
        rowu[t]       = h0;          // k = 4t .. 4t+3
        rowu[t + 256] = h1;          // k = 1024+4t ..
    } else if (blockIdx.x < M_DIM + 1024) {
        // ---- w1 transpose + bf16 round: wT[n][k] ----
        const int tid = (blockIdx.x - M_DIM) * 256 + t;   // 262144 = 512 n * 512 k4
        const int n  = tid >> 9;
        const int k4 = tid & 511;
        ushort4 h;
        h.x = f2bf(w1[(size_t)(k4 * 4 + 0) * R_DIM + n]);
        h.y = f2bf(w1[(size_t)(k4 * 4 + 1) * R_DIM + n]);
        h.z = f2bf(w1[(size_t)(k4 * 4 + 2) * R_DIM + n]);
        h.w = f2bf(w1[(size_t)(k4 * 4 + 3) * R_DIM + n]);
        ((ushort4*)wt)[(size_t)n * 512 + k4] = h;
    } else {
        // ---- zero hsum (4096 floats) ----
        zbuf[(blockIdx.x - M_DIM - 1024) * 256 + t] = 0.f;
    }
}

// ---------------------------------------------------------------------------
// Main GEMM: C[16384][512] = xn @ wT^T, bf16 MFMA, minimum-2-phase schedule:
// double-buffered 64KB LDS, next tile's global_load_lds issued BEFORE the
// current tile's ds_read+MFMA, ONE barrier per K-step (T3-minimum recipe).
// 128x128x64 tile, 4 waves (2x2 of 64x64). Linear LDS dest + pre-swizzled
// global source; XOR-swizzled ds_read_b128 (both-sides, HW-verified r3/r4).
// Epilogue: +b1, exact GELU, column-sum over 128 rows -> atomicAdd hsum.
// ---------------------------------------------------------------------------
#define BM 128
#define BN 128
#define BK 64

__global__ __launch_bounds__(256, 2) void gemm_kernel(
    const unsigned short* __restrict__ xs,   // [M] rows: 2048 bf16 in first 4KB of 8KB stride
    const unsigned short* __restrict__ wt,   // [N][K] bf16, 4KB rows
    const float* __restrict__ b1,
    float* __restrict__ hsum) {
    __shared__ __align__(16) unsigned short lds[2 * 16384];  // 64KB: 2 bufs x (A 16KB | B 16KB)

    const int t = threadIdx.x, lane = t & 63, wid = t >> 6;
    // XCD swizzle: XCD x = bid&7 owns n-column x>>1 (B-panel 2MB -> L2-resident)
    // and m-half x&1. Bijective for 512 blocks.
    const int xcd = blockIdx.x & 7, i0 = blockIdx.x >> 3;
    const int n0 = (xcd >> 1) * BN;
    const int m0 = ((xcd & 1) * 64 + i0) * BM;
    const int mw = wid >> 1, nw = wid & 1;
    const int fr = lane & 15, kg = lane >> 4, fr7 = lane & 7;

    f32x4 acc[4][4];
#pragma unroll
    for (int i = 0; i < 4; ++i)
#pragma unroll
        for (int j = 0; j < 4; ++j) acc[i][j] = (f32x4){0.f, 0.f, 0.f, 0.f};

    // Staging geometry: one 16KB tile (128 rows x 128B) = 16 x 1KB instrs;
    // wave wid issues instrs wid*4..wid*4+3 per tile. Linear LDS dest
    // (base + lane*16 by HW); source slot pre-XOR-swizzled by row&7.
    int srow[4], sgo[4], ldso[4];
#pragma unroll
    for (int ii = 0; ii < 4; ++ii) {
        const int idx = wid * 4 + ii;
        const int o = (idx << 10) + (lane << 4);
        const int r = o >> 7, sl = (o >> 4) & 7;
        srow[ii] = r;
        sgo[ii]  = ((sl ^ (r & 7)) << 4);
        ldso[ii] = (idx << 10);
    }

    int aoff[4], boff[4];
#pragma unroll
    for (int f = 0; f < 4; ++f) {
        aoff[f] = (mw * 64 + f * 16 + fr) * 128;
        boff[f] = (nw * 64 + f * 16 + fr) * 128;
    }
    const char* xb = (const char*)xs;
    const char* wb = (const char*)wt;

    auto stage = [&](int bsel, int k0b) {
        char* base = (char*)lds + bsel * 32768;
#pragma unroll
        for (int ii = 0; ii < 4; ++ii) {
            const char* a = xb + (size_t)(m0 + srow[ii]) * 8192 + k0b + sgo[ii];
            const char* b = wb + (size_t)(n0 + srow[ii]) * 4096 + k0b + sgo[ii];
            gload_lds16(a, base +     0 + ldso[ii]);
            gload_lds16(b, base + 16384 + ldso[ii]);
        }
    };

    stage(0, 0);
    __syncthreads();             // tile 0 resident
    int buf = 0;
    for (int it = 0; it < 32; ++it) {
        if (it < 31) stage(buf ^ 1, (it + 1) << 7);   // issue next tile FIRST
        const char* ab = (const char*)lds + buf * 32768;
#pragma unroll
        for (int kk = 0; kk < 2; ++kk) {
            const int sw = ((kk * 4 + kg) ^ fr7) << 4;   // swizzled 16B k-slot
            bf16x8 ah[4], bh[4];
#pragma unroll
            for (int f = 0; f < 4; ++f) {
                ah[f] = *(const bf16x8*)(ab +     0 + aoff[f] + sw);
                bh[f] = *(const bf16x8*)(ab + 16384 + boff[f] + sw);
            }
#pragma unroll
            for (int i = 0; i < 4; ++i)
#pragma unroll
                for (int j = 0; j < 4; ++j)
                    acc[i][j] = __builtin_amdgcn_mfma_f32_16x16x32_bf16(ah[i], bh[j], acc[i][j], 0, 0, 0);
        }
        __syncthreads();   // single barrier: drains vmcnt(0)+lgkmcnt(0); next buf ready
        buf ^= 1;
    }

    // Epilogue: y = acc + b1; h = exact GELU(y); per-column partial sums.
    // D layout (m89-verified): col = lane&15 (n), row = (lane>>4)*4 + reg (m).
    float* red = (float*)lds;            // [wid*4+kg][64 cols]
    float pn[4];
#pragma unroll
    for (int j = 0; j < 4; ++j) pn[j] = 0.f;
#pragma unroll
    for (int j = 0; j < 4; ++j) {
        const float bb = b1[n0 + nw * 64 + j * 16 + fr];
#pragma unroll
        for (int i = 0; i < 4; ++i)
#pragma unroll
            for (int r = 0; r < 4; ++r) {
                const float y = acc[i][j][r] + bb;
                pn[j] += 0.5f * y * (1.f + erff(y * 0.70710678118654752f));
            }
    }
#pragma unroll
    for (int j = 0; j < 4; ++j)
        red[(wid * 4 + kg) * 64 + j * 16 + fr] = pn[j];
    __syncthreads();
    if (t < 128) {
        const int nw2 = t >> 6, cl = t & 63;
        float s2 = 0.f;
#pragma unroll
        for (int mw2 = 0; mw2 < 2; ++mw2)
#pragma unroll
            for (int g = 0; g < 4; ++g)
                s2 += red[((mw2 * 2 + nw2) * 4 + g) * 64 + cl];
        atomicAdd(&hsum[(m0 >> 11) * R_DIM + n0 + t], s2);
    }
}

// ---------------------------------------------------------------------------
// Fused router (single block, 512 threads):
//   brd[b][q] = sum_r hsum[b][r]*w2[r][q] + S*b2[q]   (thread t owns q=t)
//   logits = brd@wr + br; BCE loss; argmax counts; mode.
// ---------------------------------------------------------------------------
__global__ __launch_bounds__(512) void router_kernel(const float* __restrict__ hsum,
                                                     const float* __restrict__ w2,
                                                     const float* __restrict__ b2,
                                                     const float* __restrict__ wr,
                                                     const float* __restrict__ br,
                                                     float* __restrict__ out) {
    __shared__ float hs[B_NUM * R_DIM];    // 16KB
    __shared__ float brd[B_NUM * R_DIM];   // 16KB
    __shared__ float part[8][64];
    __shared__ float lg[64];
    const int t = threadIdx.x;             // 512
    for (int i = t; i < B_NUM * R_DIM; i += 512) hs[i] = hsum[i];
    __syncthreads();

    // stage 1: thread t owns column q = t
    float acc[B_NUM] = {0, 0, 0, 0, 0, 0, 0, 0};
#pragma unroll 4
    for (int r = 0; r < R_DIM; ++r) {
        const float w = w2[(size_t)r * R_DIM + t];   // coalesced
#pragma unroll
        for (int b = 0; b < B_NUM; ++b) acc[b] = fmaf(hs[b * R_DIM + r], w, acc[b]);
    }
    const float bias2 = (float)S_NUM * b2[t];
#pragma unroll
    for (int b = 0; b < B_NUM; ++b) brd[b * R_DIM + t] = acc[b] + bias2;
    __syncthreads();

    // stage 2: logits, 8 q-groups x 64 (b,e) pairs
    const int te = t & 63, qg = t >> 6;
    const int b = te >> 3, e = te & 7;
    float s = 0.f;
    for (int q = qg; q < R_DIM; q += 8)
        s = fmaf(brd[b * R_DIM + q], wr[q * E_NUM + e], s);
    part[qg][te] = s;
    __syncthreads();
    if (qg == 0) {
        float v = br[e];
#pragma unroll
        for (int g = 0; g < 8; ++g) v += part[g][te];
        lg[te] = v;
    }
    __syncthreads();
    if (t == 0) {
        int cnt[8] = {0, 0, 0, 0, 0, 0, 0, 0};
        float loss = 0.f;
        for (int bb = 0; bb < 8; ++bb) {
            int best = 0;
            float bv = lg[bb * 8];
            for (int ee = 1; ee < 8; ++ee)
                if (lg[bb * 8 + ee] > bv) { bv = lg[bb * 8 + ee]; best = ee; }
            cnt[best]++;
            for (int ee = 0; ee < 8; ++ee) {
                const float xv = lg[bb * 8 + ee];
                loss += fmaxf(xv, 0.f) + log1pf(expf(-fabsf(xv))) - (ee == best ? xv : 0.f);
            }
        }
        out[0] = loss * (1.f / 64.f);
        int ni = 0;
        for (int ee = 1; ee < 8; ++ee)
            if (cnt[ee] > cnt[ni]) ni = ee;   // first max == smallest on ties
        out[1] = (float)ni;
    }
}

extern "C" void kernel_launch(void* const* d_in, const int* in_sizes, int n_in,
                              void* d_out, int out_size, void* d_ws, size_t ws_size,
                              hipStream_t stream) {
    float* x           = (float*)d_in[0];   // normalized+bf16-packed in place
    const float* gamma = (const float*)d_in[1];
    const float* beta  = (const float*)d_in[2];
    const float* w1    = (const float*)d_in[3];
    const float* b1    = (const float*)d_in[4];
    const float* w2    = (const float*)d_in[5];
    const float* b2    = (const float*)d_in[6];
    const float* wr    = (const float*)d_in[7];
    const float* br    = (const float*)d_in[8];
    float* out = (float*)d_out;
    float* ws  = (float*)d_ws;

    float* hsum = ws;                                    // 4096 floats (zeroed by prep)
    unsigned short* wt = (unsigned short*)(ws + 4096);   // 1M ushort (2MB)

    prep_kernel<<<dim3(M_DIM + 1024 + 16), dim3(256), 0, stream>>>(
        x, gamma, beta, w1, wt, hsum);
    gemm_kernel<<<dim3(512), dim3(256), 0, stream>>>(
        (const unsigned short*)x, wt, b1, hsum);
    router_kernel<<<dim3(1), dim3(512), 0, stream>>>(hsum, w2, b2, wr, br, out);
}

// Round 8
// 305.646 us; speedup vs baseline: 1.1852x; 1.1852x over previous
//
#include <hip/hip_runtime.h>
#include <math.h>

#define D_DIM 2048
#define R_DIM 512
#define E_NUM 8
#define B_NUM 8
#define S_NUM 2048
#define M_DIM 16384
#define LN_EPS 1e-5f

typedef __attribute__((ext_vector_type(8))) short bf16x8;
typedef __attribute__((ext_vector_type(4))) float f32x4;

// Manual RNE float->bf16 (inputs finite/normal; no NaN path needed)
__device__ __forceinline__ unsigned short f2bf(float f) {
    unsigned u = __float_as_uint(f);
    return (unsigned short)((u + 0x7FFFu + ((u >> 16) & 1u)) >> 16);
}

__device__ __forceinline__ void gload_lds16(const void* g, void* l) {
    __builtin_amdgcn_global_load_lds(
        (const __attribute__((address_space(1))) void*)g,
        (__attribute__((address_space(3))) void*)l, 16, 0, 0);
}

// ---------------------------------------------------------------------------
// Fused prep kernel, one dispatch:
//   blocks [0, 16384):      per-token LayerNorm -> bf16 in place (first 4KB/row)
//   blocks [16384, 17408):  w1[k][n] fp32 -> wT[n][k] bf16 (transpose + round)
//   blocks [17408, 17440):  zero hsum+brd (8192 floats)
// ---------------------------------------------------------------------------
__global__ __launch_bounds__(256) void prep_kernel(float* __restrict__ x,
                                                   const float* __restrict__ gamma,
                                                   const float* __restrict__ beta,
                                                   const float* __restrict__ w1,
                                                   unsigned short* __restrict__ wt,
                                                   float* __restrict__ zbuf) {
    const int t = threadIdx.x;
    if (blockIdx.x < M_DIM) {
        // ---- LayerNorm + bf16 pack, in place ----
        __shared__ float sred[8];
        float* row = x + (size_t)blockIdx.x * D_DIM;
        const float4 v0  = ((const float4*)row)[t];
        const float4 v1  = ((const float4*)row)[t + 256];
        const float4 g0  = ((const float4*)gamma)[t];
        const float4 g1  = ((const float4*)gamma)[t + 256];
        const float4 be0 = ((const float4*)beta)[t];
        const float4 be1 = ((const float4*)beta)[t + 256];

        float s  = v0.x + v0.y + v0.z + v0.w + v1.x + v1.y + v1.z + v1.w;
        float sq = v0.x*v0.x + v0.y*v0.y + v0.z*v0.z + v0.w*v0.w
                 + v1.x*v1.x + v1.y*v1.y + v1.z*v1.z + v1.w*v1.w;
#pragma unroll
        for (int off = 32; off > 0; off >>= 1) {
            s  += __shfl_down(s, off);
            sq += __shfl_down(sq, off);
        }
        if ((t & 63) == 0) { sred[(t >> 6) * 2] = s; sred[(t >> 6) * 2 + 1] = sq; }
        __syncthreads();            // also: all reads of `row` are complete
        s  = sred[0] + sred[2] + sred[4] + sred[6];
        sq = sred[1] + sred[3] + sred[5] + sred[7];
        const float mu  = s * (1.f / D_DIM);
        const float var = sq * (1.f / D_DIM) - mu * mu;
        const float rs  = rsqrtf(var + LN_EPS);

        ushort4 h0, h1;
        h0.x = f2bf(fmaf((v0.x - mu) * rs, g0.x, be0.x));
        h0.y = f2bf(fmaf((v0.y - mu) * rs, g0.y, be0.y));
        h0.z = f2bf(fmaf((v0.z - mu) * rs, g0.z, be0.z));
        h0.w = f2bf(fmaf((v0.w - mu) * rs, g0.w, be0.w));
        h1.x = f2bf(fmaf((v1.x - mu) * rs, g1.x, be1.x));
        h1.y = f2bf(fmaf((v1.y - mu) * rs, g1.y, be1.y));
        h1.z = f2bf(fmaf((v1.z - mu) * rs, g1.z, be1.z));
        h1.w = f2bf(fmaf((v1.w - mu) * rs, g1.w, be1.w));

        ushort4* rowu = (ushort4*)row;
        rowu[t]       = h0;          // k = 4t .. 4t+3
        rowu[t + 256] = h1;          // k = 1024+4t ..
    } else if (blockIdx.x < M_DIM + 1024) {
        // ---- w1 transpose + bf16 round: wT[n][k] ----
        const int tid = (blockIdx.x - M_DIM) * 256 + t;   // 262144 = 512 n * 512 k4
        const int n  = tid >> 9;
        const int k4 = tid & 511;
        ushort4 h;
        h.x = f2bf(w1[(size_t)(k4 * 4 + 0) * R_DIM + n]);
        h.y = f2bf(w1[(size_t)(k4 * 4 + 1) * R_DIM + n]);
        h.z = f2bf(w1[(size_t)(k4 * 4 + 2) * R_DIM + n]);
        h.w = f2bf(w1[(size_t)(k4 * 4 + 3) * R_DIM + n]);
        ((ushort4*)wt)[(size_t)n * 512 + k4] = h;
    } else {
        // ---- zero hsum (4096) + brd (4096) ----
        zbuf[(blockIdx.x - M_DIM - 1024) * 256 + t] = 0.f;
    }
}

// ---------------------------------------------------------------------------
// Main GEMM: C[16384][512] = xn @ wT^T, bf16 MFMA, minimum-2-phase schedule:
// double-buffered 64KB LDS, next tile's global_load_lds issued BEFORE the
// current tile's ds_read+MFMA, ONE barrier per K-step (T3-minimum recipe).
// 128x128x64 tile, 4 waves (2x2 of 64x64). Measured r4->r6: this schedule
// saved ~50us vs the 2-barrier single-buffer version. UNCHANGED from r6.
// ---------------------------------------------------------------------------
#define BM 128
#define BN 128
#define BK 64

__global__ __launch_bounds__(256, 2) void gemm_kernel(
    const unsigned short* __restrict__ xs,   // [M] rows: 2048 bf16 in first 4KB of 8KB stride
    const unsigned short* __restrict__ wt,   // [N][K] bf16, 4KB rows
    const float* __restrict__ b1,
    float* __restrict__ hsum) {
    __shared__ __align__(16) unsigned short lds[2 * 16384];  // 64KB: 2 bufs x (A 16KB | B 16KB)

    const int t = threadIdx.x, lane = t & 63, wid = t >> 6;
    // XCD swizzle: XCD x = bid&7 owns n-column x>>1 (B-panel 2MB -> L2-resident)
    // and m-half x&1. Bijective for 512 blocks.
    const int xcd = blockIdx.x & 7, i0 = blockIdx.x >> 3;
    const int n0 = (xcd >> 1) * BN;
    const int m0 = ((xcd & 1) * 64 + i0) * BM;
    const int mw = wid >> 1, nw = wid & 1;
    const int fr = lane & 15, kg = lane >> 4, fr7 = lane & 7;

    f32x4 acc[4][4];
#pragma unroll
    for (int i = 0; i < 4; ++i)
#pragma unroll
        for (int j = 0; j < 4; ++j) acc[i][j] = (f32x4){0.f, 0.f, 0.f, 0.f};

    // Staging geometry: one 16KB tile (128 rows x 128B) = 16 x 1KB instrs;
    // wave wid issues instrs wid*4..wid*4+3 per tile. Linear LDS dest
    // (base + lane*16 by HW); source slot pre-XOR-swizzled by row&7.
    int srow[4], sgo[4], ldso[4];
#pragma unroll
    for (int ii = 0; ii < 4; ++ii) {
        const int idx = wid * 4 + ii;
        const int o = (idx << 10) + (lane << 4);
        const int r = o >> 7, sl = (o >> 4) & 7;
        srow[ii] = r;
        sgo[ii]  = ((sl ^ (r & 7)) << 4);
        ldso[ii] = (idx << 10);
    }

    int aoff[4], boff[4];
#pragma unroll
    for (int f = 0; f < 4; ++f) {
        aoff[f] = (mw * 64 + f * 16 + fr) * 128;
        boff[f] = (nw * 64 + f * 16 + fr) * 128;
    }
    const char* xb = (const char*)xs;
    const char* wb = (const char*)wt;

    auto stage = [&](int bsel, int k0b) {
        char* base = (char*)lds + bsel * 32768;
#pragma unroll
        for (int ii = 0; ii < 4; ++ii) {
            const char* a = xb + (size_t)(m0 + srow[ii]) * 8192 + k0b + sgo[ii];
            const char* b = wb + (size_t)(n0 + srow[ii]) * 4096 + k0b + sgo[ii];
            gload_lds16(a, base +     0 + ldso[ii]);
            gload_lds16(b, base + 16384 + ldso[ii]);
        }
    };

    stage(0, 0);
    __syncthreads();             // tile 0 resident
    int buf = 0;
    for (int it = 0; it < 32; ++it) {
        if (it < 31) stage(buf ^ 1, (it + 1) << 7);   // issue next tile FIRST
        const char* ab = (const char*)lds + buf * 32768;
#pragma unroll
        for (int kk = 0; kk < 2; ++kk) {
            const int sw = ((kk * 4 + kg) ^ fr7) << 4;   // swizzled 16B k-slot
            bf16x8 ah[4], bh[4];
#pragma unroll
            for (int f = 0; f < 4; ++f) {
                ah[f] = *(const bf16x8*)(ab +     0 + aoff[f] + sw);
                bh[f] = *(const bf16x8*)(ab + 16384 + boff[f] + sw);
            }
#pragma unroll
            for (int i = 0; i < 4; ++i)
#pragma unroll
                for (int j = 0; j < 4; ++j)
                    acc[i][j] = __builtin_amdgcn_mfma_f32_16x16x32_bf16(ah[i], bh[j], acc[i][j], 0, 0, 0);
        }
        __syncthreads();   // single barrier: drains vmcnt(0)+lgkmcnt(0); next buf ready
        buf ^= 1;
    }

    // Epilogue: y = acc + b1; h = exact GELU(y); per-column partial sums.
    // D layout (m89-verified): col = lane&15 (n), row = (lane>>4)*4 + reg (m).
    float* red = (float*)lds;            // [wid*4+kg][64 cols]
    float pn[4];
#pragma unroll
    for (int j = 0; j < 4; ++j) pn[j] = 0.f;
#pragma unroll
    for (int j = 0; j < 4; ++j) {
        const float bb = b1[n0 + nw * 64 + j * 16 + fr];
#pragma unroll
        for (int i = 0; i < 4; ++i)
#pragma unroll
            for (int r = 0; r < 4; ++r) {
                const float y = acc[i][j][r] + bb;
                pn[j] += 0.5f * y * (1.f + erff(y * 0.70710678118654752f));
            }
    }
#pragma unroll
    for (int j = 0; j < 4; ++j)
        red[(wid * 4 + kg) * 64 + j * 16 + fr] = pn[j];
    __syncthreads();
    if (t < 128) {
        const int nw2 = t >> 6, cl = t & 63;
        float s2 = 0.f;
#pragma unroll
        for (int mw2 = 0; mw2 < 2; ++mw2)
#pragma unroll
            for (int g = 0; g < 4; ++g)
                s2 += red[((mw2 * 2 + nw2) * 4 + g) * 64 + cl];
        atomicAdd(&hsum[(m0 >> 11) * R_DIM + n0 + t], s2);
    }
}

// ---------------------------------------------------------------------------
// Router stage 1 (PARALLEL — r6's single-block fusion cost 116us, reverted):
// brd[b][q] = sum_r hsum[b][r]*w2[r][q]  (+ S*b2[q], once)
// ---------------------------------------------------------------------------
__global__ void router1_kernel(const float* __restrict__ hsum,
                               const float* __restrict__ w2,
                               const float* __restrict__ b2,
                               float* __restrict__ brd) {
    const int q  = blockIdx.x * 64 + threadIdx.x;
    const int r0 = blockIdx.y * 64;
    float acc[8] = {0, 0, 0, 0, 0, 0, 0, 0};
    for (int r = r0 + threadIdx.y; r < r0 + 64; r += 4) {
        const float w = w2[(size_t)r * R_DIM + q];
#pragma unroll
        for (int b = 0; b < 8; ++b) acc[b] = fmaf(hsum[b * R_DIM + r], w, acc[b]);
    }
    __shared__ float sred[4][8][64];
#pragma unroll
    for (int b = 0; b < 8; ++b) sred[threadIdx.y][b][threadIdx.x] = acc[b];
    __syncthreads();
    if (threadIdx.y == 0) {
        const float bias2 = (blockIdx.y == 0) ? (float)S_NUM * b2[q] : 0.f;
#pragma unroll
        for (int b = 0; b < 8; ++b) {
            float s = sred[0][b][threadIdx.x] + sred[1][b][threadIdx.x]
                    + sred[2][b][threadIdx.x] + sred[3][b][threadIdx.x] + bias2;
            atomicAdd(&brd[b * R_DIM + q], s);
        }
    }
}

// ---------------------------------------------------------------------------
// Router stage 2: logits = brd@wr + br; BCE loss, argmax counts, mode.
// Block (64,8): q-dimension parallelized over 8 groups.
// ---------------------------------------------------------------------------
__global__ void router2_kernel(const float* __restrict__ brd,
                               const float* __restrict__ wr,
                               const float* __restrict__ br,
                               float* __restrict__ out) {
    __shared__ float part[8][64];
    __shared__ float lg[64];
    const int te = threadIdx.x;           // (b,e) pair
    const int qg = threadIdx.y;           // q-group
    const int b = te >> 3, e = te & 7;
    float s = 0.f;
    for (int q = qg; q < R_DIM; q += 8)
        s = fmaf(brd[b * R_DIM + q], wr[q * E_NUM + e], s);
    part[qg][te] = s;
    __syncthreads();
    if (qg == 0) {
        float v = br[e];
#pragma unroll
        for (int g = 0; g < 8; ++g) v += part[g][te];
        lg[te] = v;
    }
    __syncthreads();
    if (te == 0 && qg == 0) {
        int cnt[8] = {0, 0, 0, 0, 0, 0, 0, 0};
        float loss = 0.f;
        for (int bb = 0; bb < 8; ++bb) {
            int best = 0;
            float bv = lg[bb * 8];
            for (int ee = 1; ee < 8; ++ee)
                if (lg[bb * 8 + ee] > bv) { bv = lg[bb * 8 + ee]; best = ee; }
            cnt[best]++;
            for (int ee = 0; ee < 8; ++ee) {
                const float xv = lg[bb * 8 + ee];
                loss += fmaxf(xv, 0.f) + log1pf(expf(-fabsf(xv))) - (ee == best ? xv : 0.f);
            }
        }
        out[0] = loss * (1.f / 64.f);
        int ni = 0;
        for (int ee = 1; ee < 8; ++ee)
            if (cnt[ee] > cnt[ni]) ni = ee;   // first max == smallest on ties
        out[1] = (float)ni;
    }
}

extern "C" void kernel_launch(void* const* d_in, const int* in_sizes, int n_in,
                              void* d_out, int out_size, void* d_ws, size_t ws_size,
                              hipStream_t stream) {
    float* x           = (float*)d_in[0];   // normalized+bf16-packed in place
    const float* gamma = (const float*)d_in[1];
    const float* beta  = (const float*)d_in[2];
    const float* w1    = (const float*)d_in[3];
    const float* b1    = (const float*)d_in[4];
    const float* w2    = (const float*)d_in[5];
    const float* b2    = (const float*)d_in[6];
    const float* wr    = (const float*)d_in[7];
    const float* br    = (const float*)d_in[8];
    float* out = (float*)d_out;
    float* ws  = (float*)d_ws;

    float* hsum = ws;                                    // 4096 floats (zeroed by prep)
    float* brd  = ws + 4096;                             // 4096 floats (zeroed by prep)
    unsigned short* wt = (unsigned short*)(ws + 8192);   // 1M ushort (2MB)

    prep_kernel<<<dim3(M_DIM + 1024 + 32), dim3(256), 0, stream>>>(
        x, gamma, beta, w1, wt, ws);
    gemm_kernel<<<dim3(512), dim3(256), 0, stream>>>(
        (const unsigned short*)x, wt, b1, hsum);
    router1_kernel<<<dim3(8, 8), dim3(64, 4), 0, stream>>>(hsum, w2, b2, brd);
    router2_kernel<<<dim3(1), dim3(64, 8), 0, stream>>>(brd, wr, br, out);
}

// Round 10
// 283.869 us; speedup vs baseline: 1.2761x; 1.0767x over previous
//
#include <hip/hip_runtime.h>
#include <math.h>

#define D_DIM 2048
#define R_DIM 512
#define E_NUM 8
#define B_NUM 8
#define S_NUM 2048
#define M_DIM 16384
#define LN_EPS 1e-5f

typedef __attribute__((ext_vector_type(8))) short bf16x8;
typedef __attribute__((ext_vector_type(4))) float f32x4;

// Manual RNE float->bf16 (inputs finite/normal; no NaN path needed)
__device__ __forceinline__ unsigned short f2bf(float f) {
    unsigned u = __float_as_uint(f);
    return (unsigned short)((u + 0x7FFFu + ((u >> 16) & 1u)) >> 16);
}

__device__ __forceinline__ void gload_lds16(const void* g, void* l) {
    __builtin_amdgcn_global_load_lds(
        (const __attribute__((address_space(1))) void*)g,
        (__attribute__((address_space(3))) void*)l, 16, 0, 0);
}

// ---------------------------------------------------------------------------
// Fused prep kernel, one dispatch:
//   [0, 16384):        per-token LayerNorm -> bf16 in place (first 4KB/row)
//   [16384, 17408):    w1[k][n] fp32 -> wT[n][k] bf16 (transpose + round)
//   [17408, 17472):    W2R[r][e] = sum_q w2[r][q]*wr[q][e]   (8 rows/block)
//   17472:             c2[e] = S*sum_q b2[q]*wr[q][e] + br[e]
//   [17473, 17489):    zero hsum (4096 floats)
// W2R/c2 have no GEMM dependency -> hidden under the BW-bound LN phase.
// ---------------------------------------------------------------------------
__global__ __launch_bounds__(256) void prep_kernel(float* __restrict__ x,
                                                   const float* __restrict__ gamma,
                                                   const float* __restrict__ beta,
                                                   const float* __restrict__ w1,
                                                   const float* __restrict__ w2,
                                                   const float* __restrict__ b2,
                                                   const float* __restrict__ wr,
                                                   const float* __restrict__ br,
                                                   unsigned short* __restrict__ wt,
                                                   float* __restrict__ w2r,
                                                   float* __restrict__ c2,
                                                   float* __restrict__ hsum) {
    const int t = threadIdx.x;
    if (blockIdx.x < M_DIM) {
        // ---- LayerNorm + bf16 pack, in place ----
        __shared__ float sred[8];
        float* row = x + (size_t)blockIdx.x * D_DIM;
        const float4 v0  = ((const float4*)row)[t];
        const float4 v1  = ((const float4*)row)[t + 256];
        const float4 g0  = ((const float4*)gamma)[t];
        const float4 g1  = ((const float4*)gamma)[t + 256];
        const float4 be0 = ((const float4*)beta)[t];
        const float4 be1 = ((const float4*)beta)[t + 256];

        float s  = v0.x + v0.y + v0.z + v0.w + v1.x + v1.y + v1.z + v1.w;
        float sq = v0.x*v0.x + v0.y*v0.y + v0.z*v0.z + v0.w*v0.w
                 + v1.x*v1.x + v1.y*v1.y + v1.z*v1.z + v1.w*v1.w;
#pragma unroll
        for (int off = 32; off > 0; off >>= 1) {
            s  += __shfl_down(s, off);
            sq += __shfl_down(sq, off);
        }
        if ((t & 63) == 0) { sred[(t >> 6) * 2] = s; sred[(t >> 6) * 2 + 1] = sq; }
        __syncthreads();            // also: all reads of `row` are complete
        s  = sred[0] + sred[2] + sred[4] + sred[6];
        sq = sred[1] + sred[3] + sred[5] + sred[7];
        const float mu  = s * (1.f / D_DIM);
        const float var = sq * (1.f / D_DIM) - mu * mu;
        const float rs  = rsqrtf(var + LN_EPS);

        ushort4 h0, h1;
        h0.x = f2bf(fmaf((v0.x - mu) * rs, g0.x, be0.x));
        h0.y = f2bf(fmaf((v0.y - mu) * rs, g0.y, be0.y));
        h0.z = f2bf(fmaf((v0.z - mu) * rs, g0.z, be0.z));
        h0.w = f2bf(fmaf((v0.w - mu) * rs, g0.w, be0.w));
        h1.x = f2bf(fmaf((v1.x - mu) * rs, g1.x, be1.x));
        h1.y = f2bf(fmaf((v1.y - mu) * rs, g1.y, be1.y));
        h1.z = f2bf(fmaf((v1.z - mu) * rs, g1.z, be1.z));
        h1.w = f2bf(fmaf((v1.w - mu) * rs, g1.w, be1.w));

        ushort4* rowu = (ushort4*)row;
        rowu[t]       = h0;          // k = 4t .. 4t+3
        rowu[t + 256] = h1;          // k = 1024+4t ..
    } else if (blockIdx.x < M_DIM + 1024) {
        // ---- w1 transpose + bf16 round: wT[n][k] ----
        const int tid = (blockIdx.x - M_DIM) * 256 + t;   // 262144 = 512 n * 512 k4
        const int n  = tid >> 9;
        const int k4 = tid & 511;
        ushort4 h;
        h.x = f2bf(w1[(size_t)(k4 * 4 + 0) * R_DIM + n]);
        h.y = f2bf(w1[(size_t)(k4 * 4 + 1) * R_DIM + n]);
        h.z = f2bf(w1[(size_t)(k4 * 4 + 2) * R_DIM + n]);
        h.w = f2bf(w1[(size_t)(k4 * 4 + 3) * R_DIM + n]);
        ((ushort4*)wt)[(size_t)n * 512 + k4] = h;
    } else if (blockIdx.x < M_DIM + 1024 + 64) {
        // ---- W2R: 8 r-rows per block ----
        __shared__ float wrt[E_NUM * R_DIM];   // wrT[e][q], 16KB
        for (int i = 0; i < 16; ++i) {
            const int g = i * 256 + t;          // 4096 = 512q * 8e
            wrt[(g & 7) * R_DIM + (g >> 3)] = wr[g];
        }
        __syncthreads();
        const int bw = blockIdx.x - (M_DIM + 1024);
        const int r  = bw * 8 + (t >> 5);
        const int l  = t & 31;
        float acc[E_NUM] = {0, 0, 0, 0, 0, 0, 0, 0};
        for (int k = 0; k < 16; ++k) {
            const int q = l + 32 * k;
            const float wv = w2[(size_t)r * R_DIM + q];
#pragma unroll
            for (int e = 0; e < E_NUM; ++e)
                acc[e] = fmaf(wv, wrt[e * R_DIM + q], acc[e]);
        }
#pragma unroll
        for (int e = 0; e < E_NUM; ++e) {
#pragma unroll
            for (int off = 16; off > 0; off >>= 1)
                acc[e] += __shfl_down(acc[e], off, 32);
        }
        if (l == 0) {
#pragma unroll
            for (int e = 0; e < E_NUM; ++e) w2r[r * E_NUM + e] = acc[e];
        }
    } else if (blockIdx.x == M_DIM + 1024 + 64) {
        // ---- c2[e] = S * sum_q b2[q]*wr[q][e] + br[e] ----
        __shared__ float part[8][E_NUM];
        float s = 0.f;
        const int e = t & 7, qg = (t >> 3) & 7;
        if (t < 64) {
            for (int q = qg; q < R_DIM; q += 8)
                s = fmaf(b2[q], wr[q * E_NUM + e], s);
        }
        if (t < 64) part[qg][e] = s;
        __syncthreads();
        if (t < E_NUM) {
            float v = 0.f;
#pragma unroll
            for (int g = 0; g < 8; ++g) v += part[g][t];
            c2[t] = fmaf((float)S_NUM, v, br[t]);
        }
    } else {
        // ---- zero hsum (4096 floats) ----
        hsum[(blockIdx.x - (M_DIM + 1024 + 65)) * 256 + t] = 0.f;
    }
}

// ---------------------------------------------------------------------------
// Main GEMM (byte-identical to r8's measured kernel):
// C[16384][512] = xn @ wT^T, bf16 MFMA, 2-phase double-buffered schedule.
// Epilogue: +b1, exact GELU, column-sum over 128 rows -> atomicAdd hsum.
// ---------------------------------------------------------------------------
#define BM 128
#define BN 128
#define BK 64

__global__ __launch_bounds__(256, 2) void gemm_kernel(
    const unsigned short* __restrict__ xs,   // [M] rows: 2048 bf16 in first 4KB of 8KB stride
    const unsigned short* __restrict__ wt,   // [N][K] bf16, 4KB rows
    const float* __restrict__ b1,
    float* __restrict__ hsum) {
    __shared__ __align__(16) unsigned short lds[2 * 16384];  // 64KB: 2 bufs x (A 16KB | B 16KB)

    const int t = threadIdx.x, lane = t & 63, wid = t >> 6;
    const int xcd = blockIdx.x & 7, i0 = blockIdx.x >> 3;
    const int n0 = (xcd >> 1) * BN;
    const int m0 = ((xcd & 1) * 64 + i0) * BM;
    const int mw = wid >> 1, nw = wid & 1;
    const int fr = lane & 15, kg = lane >> 4, fr7 = lane & 7;

    f32x4 acc[4][4];
#pragma unroll
    for (int i = 0; i < 4; ++i)
#pragma unroll
        for (int j = 0; j < 4; ++j) acc[i][j] = (f32x4){0.f, 0.f, 0.f, 0.f};

    int srow[4], sgo[4], ldso[4];
#pragma unroll
    for (int ii = 0; ii < 4; ++ii) {
        const int idx = wid * 4 + ii;
        const int o = (idx << 10) + (lane << 4);
        const int r = o >> 7, sl = (o >> 4) & 7;
        srow[ii] = r;
        sgo[ii]  = ((sl ^ (r & 7)) << 4);
        ldso[ii] = (idx << 10);
    }

    int aoff[4], boff[4];
#pragma unroll
    for (int f = 0; f < 4; ++f) {
        aoff[f] = (mw * 64 + f * 16 + fr) * 128;
        boff[f] = (nw * 64 + f * 16 + fr) * 128;
    }
    const char* xb = (const char*)xs;
    const char* wb = (const char*)wt;

    auto stage = [&](int bsel, int k0b) {
        char* base = (char*)lds + bsel * 32768;
#pragma unroll
        for (int ii = 0; ii < 4; ++ii) {
            const char* a = xb + (size_t)(m0 + srow[ii]) * 8192 + k0b + sgo[ii];
            const char* b = wb + (size_t)(n0 + srow[ii]) * 4096 + k0b + sgo[ii];
            gload_lds16(a, base +     0 + ldso[ii]);
            gload_lds16(b, base + 16384 + ldso[ii]);
        }
    };

    stage(0, 0);
    __syncthreads();             // tile 0 resident
    int buf = 0;
    for (int it = 0; it < 32; ++it) {
        if (it < 31) stage(buf ^ 1, (it + 1) << 7);   // issue next tile FIRST
        const char* ab = (const char*)lds + buf * 32768;
#pragma unroll
        for (int kk = 0; kk < 2; ++kk) {
            const int sw = ((kk * 4 + kg) ^ fr7) << 4;   // swizzled 16B k-slot
            bf16x8 ah[4], bh[4];
#pragma unroll
            for (int f = 0; f < 4; ++f) {
                ah[f] = *(const bf16x8*)(ab +     0 + aoff[f] + sw);
                bh[f] = *(const bf16x8*)(ab + 16384 + boff[f] + sw);
            }
#pragma unroll
            for (int i = 0; i < 4; ++i)
#pragma unroll
                for (int j = 0; j < 4; ++j)
                    acc[i][j] = __builtin_amdgcn_mfma_f32_16x16x32_bf16(ah[i], bh[j], acc[i][j], 0, 0, 0);
        }
        __syncthreads();   // single barrier per K-step
        buf ^= 1;
    }

    // Epilogue: y = acc + b1; h = exact GELU(y); per-column partial sums.
    float* red = (float*)lds;            // [wid*4+kg][64 cols]
    float pn[4];
#pragma unroll
    for (int j = 0; j < 4; ++j) pn[j] = 0.f;
#pragma unroll
    for (int j = 0; j < 4; ++j) {
        const float bb = b1[n0 + nw * 64 + j * 16 + fr];
#pragma unroll
        for (int i = 0; i < 4; ++i)
#pragma unroll
            for (int r = 0; r < 4; ++r) {
                const float y = acc[i][j][r] + bb;
                pn[j] += 0.5f * y * (1.f + erff(y * 0.70710678118654752f));
            }
    }
#pragma unroll
    for (int j = 0; j < 4; ++j)
        red[(wid * 4 + kg) * 64 + j * 16 + fr] = pn[j];
    __syncthreads();
    if (t < 128) {
        const int nw2 = t >> 6, cl = t & 63;
        float s2 = 0.f;
#pragma unroll
        for (int mw2 = 0; mw2 < 2; ++mw2)
#pragma unroll
            for (int g = 0; g < 4; ++g)
                s2 += red[((mw2 * 2 + nw2) * 4 + g) * 64 + cl];
        atomicAdd(&hsum[(m0 >> 11) * R_DIM + n0 + t], s2);
    }
}

// ---------------------------------------------------------------------------
// Finish kernel: logits[b][e] = sum_r hsum[b][r]*W2R[r][e] + c2[e];
// BCE loss; argmax counts; mode. One block, 512 threads, 32KB of input.
// ---------------------------------------------------------------------------
__global__ __launch_bounds__(512) void finish_kernel(const float* __restrict__ hsum,
                                                     const float* __restrict__ w2r,
                                                     const float* __restrict__ c2,
                                                     float* __restrict__ out) {
    __shared__ float hs[B_NUM * R_DIM];     // 16KB
    __shared__ float wl[R_DIM * E_NUM];     // 16KB
    __shared__ float lg[64];
    const int t = threadIdx.x;              // 512
    for (int i = t; i < B_NUM * R_DIM; i += 512) { hs[i] = hsum[i]; wl[i] = w2r[i]; }
    __syncthreads();

    // 64 (b,e) pairs x 8 r-groups; wave w handles b = w.
    const int p = t >> 3, sub = t & 7;
    const int b = p >> 3, e = p & 7;
    float s = 0.f;
    for (int r = sub; r < R_DIM; r += 8)
        s = fmaf(hs[b * R_DIM + r], wl[r * E_NUM + e], s);
#pragma unroll
    for (int off = 4; off > 0; off >>= 1) s += __shfl_down(s, off, 8);
    if (sub == 0) lg[p] = s + c2[e];
    __syncthreads();

    if (t == 0) {
        int cnt[8] = {0, 0, 0, 0, 0, 0, 0, 0};
        float loss = 0.f;
        for (int bb = 0; bb < 8; ++bb) {
            int best = 0;
            float bv = lg[bb * 8];
            for (int ee = 1; ee < 8; ++ee)
                if (lg[bb * 8 + ee] > bv) { bv = lg[bb * 8 + ee]; best = ee; }
            cnt[best]++;
            for (int ee = 0; ee < 8; ++ee) {
                const float xv = lg[bb * 8 + ee];
                loss += fmaxf(xv, 0.f) + log1pf(expf(-fabsf(xv))) - (ee == best ? xv : 0.f);
            }
        }
        out[0] = loss * (1.f / 64.f);
        int ni = 0;
        for (int ee = 1; ee < 8; ++ee)
            if (cnt[ee] > cnt[ni]) ni = ee;   // first max == smallest on ties
        out[1] = (float)ni;
    }
}

extern "C" void kernel_launch(void* const* d_in, const int* in_sizes, int n_in,
                              void* d_out, int out_size, void* d_ws, size_t ws_size,
                              hipStream_t stream) {
    float* x           = (float*)d_in[0];   // normalized+bf16-packed in place
    const float* gamma = (const float*)d_in[1];
    const float* beta  = (const float*)d_in[2];
    const float* w1    = (const float*)d_in[3];
    const float* b1    = (const float*)d_in[4];
    const float* w2    = (const float*)d_in[5];
    const float* b2    = (const float*)d_in[6];
    const float* wr    = (const float*)d_in[7];
    const float* br    = (const float*)d_in[8];
    float* out = (float*)d_out;
    float* ws  = (float*)d_ws;

    float* hsum = ws;                                    // [0,4096) floats (zeroed by prep)
    float* w2r  = ws + 4096;                             // [4096,8192)
    float* c2   = ws + 8192;                             // [8192,8200)
    unsigned short* wt = (unsigned short*)(ws + 8448);   // 1M ushort (2MB)

    prep_kernel<<<dim3(M_DIM + 1024 + 65 + 16), dim3(256), 0, stream>>>(
        x, gamma, beta, w1, w2, b2, wr, br, wt, w2r, c2, hsum);
    gemm_kernel<<<dim3(512), dim3(256), 0, stream>>>(
        (const unsigned short*)x, wt, b1, hsum);
    finish_kernel<<<dim3(1), dim3(512), 0, stream>>>(hsum, w2r, c2, out);
}